// Round 1
// baseline (5990.929 us; speedup 1.0000x reference)
//
#include <hip/hip_runtime.h>

#define NN 100000
#define NE 600000
#define DD 128
#define NL 3
#define NG 64
#define LN_EPS 1e-5f

// ---------------- fused GEMM (+agg) + ReLU (+LayerNorm) ----------------
template<bool ADD_AGG, bool DO_LN>
__global__ __launch_bounds__(256)
void gemm_fused(const float* __restrict__ X, const float* __restrict__ agg,
                const float* __restrict__ Wg, const float* __restrict__ bg,
                const float* __restrict__ lng, const float* __restrict__ lnb,
                float* __restrict__ Y) {
  __shared__ float Wl[DD * DD];       // 64 KB
  __shared__ float rowsL[16][DD];     // 8 KB
  const int t = threadIdx.x;
  const int tx = t & 63;
  const int ty = t >> 6;

  { // stage W: 16384 floats, 64 per thread, coalesced float4
    const float4* Wg4 = (const float4*)Wg;
    float4* Wl4 = (float4*)Wl;
#pragma unroll
    for (int i = 0; i < 16; ++i) Wl4[t + 256 * i] = Wg4[t + 256 * i];
  }
  const float b0 = bg[tx], b1 = bg[tx + 64];
  float g0 = 0.f, g1 = 0.f, q0 = 0.f, q1 = 0.f;
  if (DO_LN) { g0 = lng[tx]; g1 = lng[tx + 64]; q0 = lnb[tx]; q1 = lnb[tx + 64]; }

  const int rowbase = blockIdx.x * 64;
#pragma unroll 1
  for (int pass = 0; pass < 4; ++pass) {
    const int r0 = rowbase + pass * 16;
    if (r0 >= NN) break;                 // uniform across block
    __syncthreads();                     // protect rowsL reuse (and W stage on pass 0)
    { // stage 16 rows (optionally h+agg), 8 floats per thread
      const int rr = t >> 4;
      const int cc = (t & 15) << 3;
      const int row = r0 + rr;
      float4 v0 = {0, 0, 0, 0}, v1 = {0, 0, 0, 0};
      if (row < NN) {
        const float* p = X + (size_t)row * DD + cc;
        v0 = *(const float4*)p;
        v1 = *(const float4*)(p + 4);
        if (ADD_AGG) {
          const float* q = agg + (size_t)row * DD + cc;
          const float4 a0 = *(const float4*)q;
          const float4 a1 = *(const float4*)(q + 4);
          v0.x += a0.x; v0.y += a0.y; v0.z += a0.z; v0.w += a0.w;
          v1.x += a1.x; v1.y += a1.y; v1.z += a1.z; v1.w += a1.w;
        }
      }
      *(float4*)&rowsL[rr][cc] = v0;
      *(float4*)&rowsL[rr][cc + 4] = v1;
    }
    __syncthreads();

    float acc00 = 0.f, acc01 = 0.f, acc10 = 0.f, acc11 = 0.f;
    float acc20 = 0.f, acc21 = 0.f, acc30 = 0.f, acc31 = 0.f;
    const int rb = ty * 4;
#pragma unroll
    for (int k = 0; k < DD; k += 4) {
      const float4 a0 = *(const float4*)&rowsL[rb + 0][k];
      const float4 a1 = *(const float4*)&rowsL[rb + 1][k];
      const float4 a2 = *(const float4*)&rowsL[rb + 2][k];
      const float4 a3 = *(const float4*)&rowsL[rb + 3][k];
      const float* wp = &Wl[k * DD];
#pragma unroll
      for (int kk = 0; kk < 4; ++kk) {
        const float w0 = wp[kk * DD + tx];
        const float w1 = wp[kk * DD + tx + 64];
        const float e0 = (&a0.x)[kk], e1 = (&a1.x)[kk];
        const float e2 = (&a2.x)[kk], e3 = (&a3.x)[kk];
        acc00 += e0 * w0; acc01 += e0 * w1;
        acc10 += e1 * w0; acc11 += e1 * w1;
        acc20 += e2 * w0; acc21 += e2 * w1;
        acc30 += e3 * w0; acc31 += e3 * w1;
      }
    }

    const float accs[4][2] = {{acc00, acc01}, {acc10, acc11},
                              {acc20, acc21}, {acc30, acc31}};
#pragma unroll
    for (int ri = 0; ri < 4; ++ri) {
      const int row = r0 + rb + ri;
      float z0 = fmaxf(accs[ri][0] + b0, 0.f);
      float z1 = fmaxf(accs[ri][1] + b1, 0.f);
      if (DO_LN) {
        float s = z0 + z1, s2 = z0 * z0 + z1 * z1;
#pragma unroll
        for (int off = 32; off; off >>= 1) {
          s += __shfl_xor(s, off);
          s2 += __shfl_xor(s2, off);
        }
        const float mu = s * (1.f / DD);
        const float var = s2 * (1.f / DD) - mu * mu;
        const float inv = rsqrtf(var + LN_EPS);
        z0 = (z0 - mu) * inv * g0 + q0;
        z1 = (z1 - mu) * inv * g1 + q1;
      }
      if (row < NN) {
        Y[(size_t)row * DD + tx] = z0;
        Y[(size_t)row * DD + tx + 64] = z1;
      }
    }
  }
}

// ---------------- edge scatter-add: agg[dst] += h[src] ----------------
__global__ __launch_bounds__(256)
void scatter_add(const float* __restrict__ h, const int* __restrict__ src,
                 const int* __restrict__ dst, float* __restrict__ agg) {
  const int t = blockIdx.x * 256 + threadIdx.x;
  const int e = t >> 5;
  if (e >= NE) return;
  const int c = (t & 31) << 2;
  const int s = src[e], d = dst[e];
  const float4 v = *(const float4*)(h + (size_t)s * DD + c);
  float* p = agg + (size_t)d * DD + c;
  __hip_atomic_fetch_add(p + 0, v.x, __ATOMIC_RELAXED, __HIP_MEMORY_SCOPE_AGENT);
  __hip_atomic_fetch_add(p + 1, v.y, __ATOMIC_RELAXED, __HIP_MEMORY_SCOPE_AGENT);
  __hip_atomic_fetch_add(p + 2, v.z, __ATOMIC_RELAXED, __HIP_MEMORY_SCOPE_AGENT);
  __hip_atomic_fetch_add(p + 3, v.w, __ATOMIC_RELAXED, __HIP_MEMORY_SCOPE_AGENT);
}

// ---------------- segmented pool (batch_ids sorted) ----------------
__global__ __launch_bounds__(128)
void pool_kernel(const float* __restrict__ h, const int* __restrict__ batch,
                 float* __restrict__ sums, float* __restrict__ counts) {
  const int c = threadIdx.x;
  const int base = blockIdx.x * 64;
  const int end = (base + 64 < NN) ? base + 64 : NN;
  int cur = batch[base];
  float acc = 0.f, cnt = 0.f;
  for (int r = base; r < end; ++r) {
    const int g = batch[r];
    if (g != cur) {
      __hip_atomic_fetch_add(&sums[cur * DD + c], acc, __ATOMIC_RELAXED, __HIP_MEMORY_SCOPE_AGENT);
      if (c == 0)
        __hip_atomic_fetch_add(&counts[cur], cnt, __ATOMIC_RELAXED, __HIP_MEMORY_SCOPE_AGENT);
      acc = 0.f; cnt = 0.f; cur = g;
    }
    acc += h[(size_t)r * DD + c];
    cnt += 1.f;
  }
  __hip_atomic_fetch_add(&sums[cur * DD + c], acc, __ATOMIC_RELAXED, __HIP_MEMORY_SCOPE_AGENT);
  if (c == 0)
    __hip_atomic_fetch_add(&counts[cur], cnt, __ATOMIC_RELAXED, __HIP_MEMORY_SCOPE_AGENT);
}

__global__ __launch_bounds__(256)
void finalize_kernel(const float* __restrict__ sums, const float* __restrict__ counts,
                     float* __restrict__ out) {
  const int i = blockIdx.x * 256 + threadIdx.x;
  if (i >= NG * DD) return;
  out[i] = sums[i] / fmaxf(counts[i >> 7], 1.f);
}

extern "C" void kernel_launch(void* const* d_in, const int* in_sizes, int n_in,
                              void* d_out, int out_size, void* d_ws, size_t ws_size,
                              hipStream_t stream) {
  const float* x     = (const float*)d_in[0];
  const int*   ei    = (const int*)d_in[1];
  const int*   batch = (const int*)d_in[2];
  const float* projW = (const float*)d_in[3];
  const float* projb = (const float*)d_in[4];
  const float* mlpW  = (const float*)d_in[5];
  const float* mlpb  = (const float*)d_in[6];
  const float* lng   = (const float*)d_in[7];
  const float* lnb   = (const float*)d_in[8];
  float* out = (float*)d_out;

  float* h      = (float*)d_ws;                 // NN*DD floats
  float* agg    = h + (size_t)NN * DD;          // NN*DD floats
  float* sums   = agg + (size_t)NN * DD;        // NG*DD floats
  float* counts = sums + NG * DD;               // NG floats

  const int* src = ei;
  const int* dst = ei + NE;

  const int gemm_blocks = (NN + 63) / 64;       // 1563

  // h = relu(x @ projW + projb)
  gemm_fused<false, false><<<gemm_blocks, 256, 0, stream>>>(
      x, nullptr, projW, projb, nullptr, nullptr, h);

  for (int l = 0; l < NL; ++l) {
    hipMemsetAsync(agg, 0, (size_t)NN * DD * sizeof(float), stream);
    scatter_add<<<(NE * 32) / 256, 256, 0, stream>>>(h, src, dst, agg);
    // h = LN(relu((h + agg) @ W_l + b_l))   (in-place: row r depends only on row r)
    gemm_fused<true, true><<<gemm_blocks, 256, 0, stream>>>(
        h, agg, mlpW + (size_t)l * DD * DD, mlpb + (size_t)l * DD,
        lng + (size_t)l * DD, lnb + (size_t)l * DD, h);
  }

  hipMemsetAsync(sums, 0, (size_t)(NG * DD + NG) * sizeof(float), stream);
  pool_kernel<<<(NN + 63) / 64, 128, 0, stream>>>(h, batch, sums, counts);
  finalize_kernel<<<(NG * DD + 255) / 256, 256, 0, stream>>>(sums, counts, out);
}

// Round 2
// 463.500 us; speedup vs baseline: 12.9254x; 12.9254x over previous
//
#include <hip/hip_runtime.h>
#include <hip/hip_bf16.h>

#define NN 100000
#define NE 600000
#define DD 128
#define NL 3
#define NG 64
#define LN_EPS 1e-5f

typedef __attribute__((ext_vector_type(8))) short short8v;
typedef __attribute__((ext_vector_type(8))) unsigned short ushort8v;
typedef __attribute__((ext_vector_type(4))) float f32x4;
typedef unsigned short ushort;

// ============ CSR build ============
__global__ __launch_bounds__(256)
void count_kernel(const int* __restrict__ dst, int* __restrict__ deg) {
  const int e = blockIdx.x * 256 + threadIdx.x;
  if (e < NE) atomicAdd(&deg[dst[e]], 1);
}

// exclusive scan, 1024 elems/block (4/thread)
__global__ __launch_bounds__(256)
void scan_a(const int* __restrict__ deg, int* __restrict__ off, int* __restrict__ btot) {
  __shared__ int wsum[4];
  const int t = threadIdx.x, lane = t & 63, wid = t >> 6;
  const int base = blockIdx.x * 1024 + t * 4;
  int4 d = {0, 0, 0, 0};
  if (base < NN) d = *(const int4*)(deg + base);   // NN % 4 == 0
  const int s0 = d.x, s1 = s0 + d.y, s2 = s1 + d.z, s3 = s2 + d.w;
  int v = s3;
#pragma unroll
  for (int o = 1; o < 64; o <<= 1) { const int u = __shfl_up(v, o); if (lane >= o) v += u; }
  if (lane == 63) wsum[wid] = v;
  __syncthreads();
  if (t == 0) {
    int a = 0;
#pragma unroll
    for (int i = 0; i < 4; ++i) { const int x = wsum[i]; wsum[i] = a; a += x; }
    btot[blockIdx.x] = a;
  }
  __syncthreads();
  const int texcl = wsum[wid] + v - s3;
  if (base < NN) {
    const int4 o4 = {texcl, texcl + s0, texcl + s1, texcl + s2};
    *(int4*)(off + base) = o4;
  }
}

__global__ __launch_bounds__(128)
void scan_b(int* __restrict__ btot, int nb) {
  __shared__ int wsum[2];
  const int t = threadIdx.x, lane = t & 63, wid = t >> 6;
  const int x = (t < nb) ? btot[t] : 0;
  int v = x;
#pragma unroll
  for (int o = 1; o < 64; o <<= 1) { const int u = __shfl_up(v, o); if (lane >= o) v += u; }
  if (lane == 63) wsum[wid] = v;
  __syncthreads();
  if (t == 0) { const int w0 = wsum[0]; wsum[0] = 0; wsum[1] = w0; }
  __syncthreads();
  const int excl = wsum[wid] + v - x;
  if (t < nb) btot[t] = excl;
}

__global__ __launch_bounds__(256)
void scan_c(int* __restrict__ off, const int* __restrict__ btot) {
  const int i = blockIdx.x * 256 + threadIdx.x;
  if (i < NN) off[i] += btot[i >> 10];
}

// fill: atomicAdd turns off[] starts into ends; csr gets src per dst bucket
__global__ __launch_bounds__(256)
void fill_kernel(const int* __restrict__ src, const int* __restrict__ dst,
                 int* __restrict__ off, int* __restrict__ csr) {
  const int e = blockIdx.x * 256 + threadIdx.x;
  if (e < NE) {
    const int p = atomicAdd(&off[dst[e]], 1);
    csr[p] = src[e];
  }
}

// ============ aggregate: xa[v] = h[v] + sum_{s in N(v)} h[s] ============
__global__ __launch_bounds__(256)
void agg_kernel(const float* __restrict__ h, const int* __restrict__ csr,
                const int* __restrict__ offE, float* __restrict__ xa) {
  const int t = threadIdx.x, lane = t & 63;
  const int v = blockIdx.x * 4 + (t >> 6);
  if (v >= NN) return;
  const int s0 = (v == 0) ? 0 : offE[v - 1];
  const int s1 = offE[v];
  const float2* hp = (const float2*)h;
  float2 a = hp[(size_t)v * 64 + lane];           // GIN self-term (eps=0)
  for (int i = s0; i < s1; ++i) {
    const int s = csr[i];                          // wave-uniform -> scalar load
    const float2 b = hp[(size_t)s * 64 + lane];
    a.x += b.x; a.y += b.y;
  }
  ((float2*)xa)[(size_t)v * 64 + lane] = a;
}

// ============ weight prep: fragment-ordered bf16 hi/lo ============
// layout per matrix: [kk:4][nf:8][hl:2][lane:64][8 bf16]  = 32768 ushort
__global__ __launch_bounds__(256)
void wprep_kernel(const float* __restrict__ projW, const float* __restrict__ mlpW,
                  ushort* __restrict__ Wp) {
  const int tid = blockIdx.x * 256 + threadIdx.x;   // 8192 total
  const int lane = tid & 63;
  const int fid = tid >> 6;                         // 0..127
  const int mat = fid >> 5;
  const int rem = fid & 31;
  const int kk = rem >> 3, nf = rem & 7;
  const float* W = (mat == 0) ? projW : (mlpW + (size_t)(mat - 1) * DD * DD);
  const int k0 = kk * 32 + (lane >> 4) * 8;
  const int col = nf * 16 + (lane & 15);
  ushort8v hv, lv;
#pragma unroll
  for (int j = 0; j < 8; ++j) {
    const float f = W[(size_t)(k0 + j) * DD + col];
    __hip_bfloat16 bh = __float2bfloat16(f);
    __hip_bfloat16 bl = __float2bfloat16(f - __bfloat162float(bh));
    hv[j] = *(ushort*)&bh;
    lv[j] = *(ushort*)&bl;
  }
  ushort* base = Wp + (size_t)mat * 32768;
  *(ushort8v*)(base + ((size_t)((kk * 8 + nf) * 2 + 0) * 64 + lane) * 8) = hv;
  *(ushort8v*)(base + ((size_t)((kk * 8 + nf) * 2 + 1) * 64 + lane) * 8) = lv;
}

// ============ MFMA GEMM: Y = [LN](relu(X @ W + b)) ============
// block 256 = 4 waves; block tile 64 rows x 128 cols; wave w: rows w*16..+16.
// fp32 via bf16 split: Ahi*Bhi + Alo*Bhi + Ahi*Blo.
template<bool DO_LN>
__global__ __launch_bounds__(256)
void gemm_mfma(const float* __restrict__ X, const ushort* __restrict__ Wp,
               const float* __restrict__ bias,
               const float* __restrict__ lng, const float* __restrict__ lnb,
               float* __restrict__ Y) {
  __shared__ ushort AH[64 * 128];
  __shared__ ushort AL[64 * 128];
  const int t = threadIdx.x, lane = t & 63, w = t >> 6;
  const int r0 = blockIdx.x * 64;

  { // stage 64 rows of X -> bf16 hi/lo in LDS, chunk-swizzled (ch ^= row&7)
    const int row = t >> 2;
    const int cb = (t & 3) * 4;
    const int grow = r0 + row;
    const float4* Xp = (const float4*)(X + (size_t)grow * DD);
#pragma unroll
    for (int i = 0; i < 4; ++i) {
      const int ch = cb + i;
      float4 va = {0, 0, 0, 0}, vb = {0, 0, 0, 0};
      if (grow < NN) { va = Xp[ch * 2]; vb = Xp[ch * 2 + 1]; }
      const float fa[8] = {va.x, va.y, va.z, va.w, vb.x, vb.y, vb.z, vb.w};
      ushort8v hv, lv;
#pragma unroll
      for (int j = 0; j < 8; ++j) {
        __hip_bfloat16 bh = __float2bfloat16(fa[j]);
        const float fh = __bfloat162float(bh);
        __hip_bfloat16 bl = __float2bfloat16(fa[j] - fh);
        hv[j] = *(ushort*)&bh;
        lv[j] = *(ushort*)&bl;
      }
      const int idx = (row * 16 + (ch ^ (row & 7))) * 8;
      *(ushort8v*)&AH[idx] = hv;
      *(ushort8v*)&AL[idx] = lv;
    }
  }
  __syncthreads();

  f32x4 acc[8];
#pragma unroll
  for (int nf = 0; nf < 8; ++nf) acc[nf] = (f32x4){0.f, 0.f, 0.f, 0.f};

  const int arow = w * 16 + (lane & 15);
  const int sw = arow & 7;
#pragma unroll
  for (int kk = 0; kk < 4; ++kk) {
    const int ch = kk * 4 + (lane >> 4);
    const int aidx = (arow * 16 + (ch ^ sw)) * 8;
    const short8v ah = *(const short8v*)&AH[aidx];
    const short8v al = *(const short8v*)&AL[aidx];
#pragma unroll
    for (int nf = 0; nf < 8; ++nf) {
      const ushort* bp = Wp + ((size_t)((kk * 8 + nf) * 2) * 64 + lane) * 8;
      const short8v bh = *(const short8v*)bp;
      const short8v bl = *(const short8v*)(bp + 64 * 8);
      acc[nf] = __builtin_amdgcn_mfma_f32_16x16x32_bf16(ah, bh, acc[nf], 0, 0, 0);
      acc[nf] = __builtin_amdgcn_mfma_f32_16x16x32_bf16(al, bh, acc[nf], 0, 0, 0);
      acc[nf] = __builtin_amdgcn_mfma_f32_16x16x32_bf16(ah, bl, acc[nf], 0, 0, 0);
    }
  }

  // epilogue: D[row][col], row = w*16 + (lane>>4)*4 + r, col = nf*16 + (lane&15)
  const int colb = lane & 15;
  float bias8[8], g8[8], q8[8];
#pragma unroll
  for (int nf = 0; nf < 8; ++nf) {
    bias8[nf] = bias[nf * 16 + colb];
    if (DO_LN) { g8[nf] = lng[nf * 16 + colb]; q8[nf] = lnb[nf * 16 + colb]; }
  }
#pragma unroll
  for (int r = 0; r < 4; ++r) {
    const int grow = r0 + w * 16 + (lane >> 4) * 4 + r;
    float z[8];
    float s = 0.f, s2 = 0.f;
#pragma unroll
    for (int nf = 0; nf < 8; ++nf) {
      z[nf] = fmaxf(acc[nf][r] + bias8[nf], 0.f);
      s += z[nf];
      s2 += z[nf] * z[nf];
    }
    if (DO_LN) {
#pragma unroll
      for (int o = 1; o < 16; o <<= 1) { s += __shfl_xor(s, o); s2 += __shfl_xor(s2, o); }
      const float mu = s * (1.f / DD);
      const float inv = rsqrtf(s2 * (1.f / DD) - mu * mu + LN_EPS);
#pragma unroll
      for (int nf = 0; nf < 8; ++nf) z[nf] = (z[nf] - mu) * inv * g8[nf] + q8[nf];
    }
    if (grow < NN) {
      float* yp = Y + (size_t)grow * DD + colb;
#pragma unroll
      for (int nf = 0; nf < 8; ++nf) yp[nf * 16] = z[nf];
    }
  }
}

// ============ pool ============
__global__ __launch_bounds__(128)
void pool_kernel(const float* __restrict__ h, const int* __restrict__ batch,
                 float* __restrict__ sums, float* __restrict__ counts) {
  const int c = threadIdx.x;
  const int base = blockIdx.x * 64;
  const int end = (base + 64 < NN) ? base + 64 : NN;
  int cur = batch[base];
  float acc = 0.f, cnt = 0.f;
  for (int r = base; r < end; ++r) {
    const int g = batch[r];
    if (g != cur) {
      __hip_atomic_fetch_add(&sums[cur * DD + c], acc, __ATOMIC_RELAXED, __HIP_MEMORY_SCOPE_AGENT);
      if (c == 0)
        __hip_atomic_fetch_add(&counts[cur], cnt, __ATOMIC_RELAXED, __HIP_MEMORY_SCOPE_AGENT);
      acc = 0.f; cnt = 0.f; cur = g;
    }
    acc += h[(size_t)r * DD + c];
    cnt += 1.f;
  }
  __hip_atomic_fetch_add(&sums[cur * DD + c], acc, __ATOMIC_RELAXED, __HIP_MEMORY_SCOPE_AGENT);
  if (c == 0)
    __hip_atomic_fetch_add(&counts[cur], cnt, __ATOMIC_RELAXED, __HIP_MEMORY_SCOPE_AGENT);
}

__global__ __launch_bounds__(256)
void finalize_kernel(const float* __restrict__ sums, const float* __restrict__ counts,
                     float* __restrict__ out) {
  const int i = blockIdx.x * 256 + threadIdx.x;
  if (i >= NG * DD) return;
  out[i] = sums[i] / fmaxf(counts[i >> 7], 1.f);
}

extern "C" void kernel_launch(void* const* d_in, const int* in_sizes, int n_in,
                              void* d_out, int out_size, void* d_ws, size_t ws_size,
                              hipStream_t stream) {
  const float* x     = (const float*)d_in[0];
  const int*   ei    = (const int*)d_in[1];
  const int*   batch = (const int*)d_in[2];
  const float* projW = (const float*)d_in[3];
  const float* projb = (const float*)d_in[4];
  const float* mlpW  = (const float*)d_in[5];
  const float* mlpb  = (const float*)d_in[6];
  const float* lng   = (const float*)d_in[7];
  const float* lnb   = (const float*)d_in[8];
  float* out = (float*)d_out;

  char* ws = (char*)d_ws;
  float* h      = (float*)(ws + 0);                       // 51,200,000 B
  float* xa     = (float*)(ws + 51200000);                // 51,200,000 B
  int*   csr    = (int*)  (ws + 102400000);               //  2,400,000 B
  int*   deg    = (int*)  (ws + 104800000);               //    400,000 B
  int*   off    = (int*)  (ws + 105200000);               //    400,000 B
  int*   btot   = (int*)  (ws + 105600000);               //        512 B
  ushort* Wp    = (ushort*)(ws + 105600512);              //    262,144 B
  float* sums   = (float*)(ws + 105862656);               //     32,768 B
  float* counts = (float*)(ws + 105895424);               //        256 B

  const int* src = ei;
  const int* dst = ei + NE;

  // ---- CSR build (once; reused by all 3 layers) ----
  hipMemsetAsync(deg, 0, NN * sizeof(int), stream);
  count_kernel<<<(NE + 255) / 256, 256, 0, stream>>>(dst, deg);
  scan_a<<<(NN + 1023) / 1024, 256, 0, stream>>>(deg, off, btot);
  scan_b<<<1, 128, 0, stream>>>(btot, (NN + 1023) / 1024);
  scan_c<<<(NN + 255) / 256, 256, 0, stream>>>(off, btot);
  fill_kernel<<<(NE + 255) / 256, 256, 0, stream>>>(src, dst, off, csr);

  // ---- weight prep ----
  wprep_kernel<<<32, 256, 0, stream>>>(projW, mlpW, Wp);

  const int gemm_blocks = (NN + 63) / 64;   // 1563

  // h = relu(x @ projW + projb)
  gemm_mfma<false><<<gemm_blocks, 256, 0, stream>>>(x, Wp, projb, nullptr, nullptr, h);

  for (int l = 0; l < NL; ++l) {
    agg_kernel<<<(NN + 3) / 4, 256, 0, stream>>>(h, csr, off, xa);
    gemm_mfma<true><<<gemm_blocks, 256, 0, stream>>>(
        xa, Wp + (size_t)(1 + l) * 32768, mlpb + (size_t)l * DD,
        lng + (size_t)l * DD, lnb + (size_t)l * DD, h);
  }

  hipMemsetAsync(sums, 0, (size_t)(NG * DD + NG) * sizeof(float), stream);
  pool_kernel<<<(NN + 63) / 64, 128, 0, stream>>>(h, batch, sums, counts);
  finalize_kernel<<<(NG * DD + 255) / 256, 256, 0, stream>>>(sums, counts, out);
}

// Round 3
// 391.122 us; speedup vs baseline: 15.3173x; 1.1851x over previous
//
#include <hip/hip_runtime.h>
#include <hip/hip_bf16.h>

#define NN 100000
#define NE 600000
#define DD 128
#define NL 3
#define NG 64
#define LN_EPS 1e-5f

typedef __attribute__((ext_vector_type(8))) short short8v;
typedef __attribute__((ext_vector_type(8))) unsigned short ushort8v;
typedef __attribute__((ext_vector_type(4))) float f32x4;
typedef unsigned short ushort;
typedef unsigned int uint;

// unpack dword of 2 bf16 (cols 2l, 2l+1) to fp32
__device__ inline float2 unpk2(uint u) {
  float2 r;
  r.x = __uint_as_float(u << 16);
  r.y = __uint_as_float(u & 0xffff0000u);
  return r;
}

// split fp32 pair -> (hi bf16 pair, lo bf16 pair); hi = truncate, lo = RNE(residual)
__device__ inline void split2(float ax, float ay, uint& hi2, uint& lo2) {
  const uint ux = __float_as_uint(ax), uy = __float_as_uint(ay);
  hi2 = (ux >> 16) | (uy & 0xffff0000u);
  const float rx = ax - __uint_as_float(ux & 0xffff0000u);
  const float ry = ay - __uint_as_float(uy & 0xffff0000u);
  __hip_bfloat16 bx = __float2bfloat16(rx), by = __float2bfloat16(ry);
  lo2 = (uint)*(ushort*)&bx | ((uint)*(ushort*)&by << 16);
}

// ============ CSR build ============
__global__ __launch_bounds__(256)
void count_kernel(const int* __restrict__ dst, int* __restrict__ deg) {
  const int e = blockIdx.x * 256 + threadIdx.x;
  if (e < NE) atomicAdd(&deg[dst[e]], 1);
}

__global__ __launch_bounds__(256)
void scan_a(const int* __restrict__ deg, int* __restrict__ off, int* __restrict__ btot) {
  __shared__ int wsum[4];
  const int t = threadIdx.x, lane = t & 63, wid = t >> 6;
  const int base = blockIdx.x * 1024 + t * 4;
  int4 d = {0, 0, 0, 0};
  if (base < NN) d = *(const int4*)(deg + base);
  const int s0 = d.x, s1 = s0 + d.y, s2 = s1 + d.z, s3 = s2 + d.w;
  int v = s3;
#pragma unroll
  for (int o = 1; o < 64; o <<= 1) { const int u = __shfl_up(v, o); if (lane >= o) v += u; }
  if (lane == 63) wsum[wid] = v;
  __syncthreads();
  if (t == 0) {
    int a = 0;
#pragma unroll
    for (int i = 0; i < 4; ++i) { const int x = wsum[i]; wsum[i] = a; a += x; }
    btot[blockIdx.x] = a;
  }
  __syncthreads();
  const int texcl = wsum[wid] + v - s3;
  if (base < NN) {
    const int4 o4 = {texcl, texcl + s0, texcl + s1, texcl + s2};
    *(int4*)(off + base) = o4;
  }
}

__global__ __launch_bounds__(128)
void scan_b(int* __restrict__ btot, int nb) {
  __shared__ int wsum[2];
  const int t = threadIdx.x, lane = t & 63, wid = t >> 6;
  const int x = (t < nb) ? btot[t] : 0;
  int v = x;
#pragma unroll
  for (int o = 1; o < 64; o <<= 1) { const int u = __shfl_up(v, o); if (lane >= o) v += u; }
  if (lane == 63) wsum[wid] = v;
  __syncthreads();
  if (t == 0) { const int w0 = wsum[0]; wsum[0] = 0; wsum[1] = w0; }
  __syncthreads();
  const int excl = wsum[wid] + v - x;
  if (t < nb) btot[t] = excl;
}

__global__ __launch_bounds__(256)
void scan_c(int* __restrict__ off, const int* __restrict__ btot) {
  const int i = blockIdx.x * 256 + threadIdx.x;
  if (i < NN) off[i] += btot[i >> 10];
}

__global__ __launch_bounds__(256)
void fill_kernel(const int* __restrict__ src, const int* __restrict__ dst,
                 int* __restrict__ off, int* __restrict__ csr) {
  const int e = blockIdx.x * 256 + threadIdx.x;
  if (e < NE) {
    const int p = atomicAdd(&off[dst[e]], 1);
    csr[p] = src[e];
  }
}

// ============ weight prep: fragment-ordered bf16 hi/lo ============
__global__ __launch_bounds__(256)
void wprep_kernel(const float* __restrict__ projW, const float* __restrict__ mlpW,
                  ushort* __restrict__ Wp) {
  const int tid = blockIdx.x * 256 + threadIdx.x;   // 8192 total
  const int lane = tid & 63;
  const int fid = tid >> 6;                         // 0..127
  const int mat = fid >> 5;
  const int rem = fid & 31;
  const int kk = rem >> 3, nf = rem & 7;
  const float* W = (mat == 0) ? projW : (mlpW + (size_t)(mat - 1) * DD * DD);
  const int k0 = kk * 32 + (lane >> 4) * 8;
  const int col = nf * 16 + (lane & 15);
  ushort8v hv, lv;
#pragma unroll
  for (int j = 0; j < 8; ++j) {
    const float f = W[(size_t)(k0 + j) * DD + col];
    __hip_bfloat16 bh = __float2bfloat16(f);
    __hip_bfloat16 bl = __float2bfloat16(f - __bfloat162float(bh));
    hv[j] = *(ushort*)&bh;
    lv[j] = *(ushort*)&bl;
  }
  ushort* base = Wp + (size_t)mat * 32768;
  *(ushort8v*)(base + ((size_t)((kk * 8 + nf) * 2 + 0) * 64 + lane) * 8) = hv;
  *(ushort8v*)(base + ((size_t)((kk * 8 + nf) * 2 + 1) * 64 + lane) * 8) = lv;
}

// ============ fused [gather-sum +] GEMM + ReLU [+ LN] ============
// MODE 0: proj  — X = Xf (fp32), no gather, no LN
// MODE 1: layer — X = Hin(bf16) row + sum of CSR neighbors (fp32 accum), LN
// block 256 = 4 waves, tile 64 rows x 128 cols. Wave w owns rows w*16..+15:
// stages ONLY those rows (wave-private LDS slice -> NO __syncthreads) and
// consumes them as its A-frags. X split hi/lo bf16; W pre-split (wprep).
template<int MODE>
__global__ __launch_bounds__(256)
void gemm_node(const float* __restrict__ Xf, const ushort* __restrict__ Hin,
               const int* __restrict__ csr, const int* __restrict__ offE,
               const ushort* __restrict__ Wp, const float* __restrict__ bias,
               const float* __restrict__ lng, const float* __restrict__ lnb,
               ushort* __restrict__ Hout) {
  __shared__ ushort AH[64 * 128];
  __shared__ ushort AL[64 * 128];
  const int t = threadIdx.x, lane = t & 63, w = t >> 6;
  const int r0 = blockIdx.x * 64;

  // ---- stage 16 rows (wave-private) ----
  const uint* hu = (const uint*)Hin;
#pragma unroll 1
  for (int rr = 0; rr < 16; ++rr) {
    const int row = w * 16 + rr;
    const int v = r0 + row;
    float ax = 0.f, ay = 0.f;
    if (v < NN) {
      if (MODE == 0) {
        const float2 s = *(const float2*)(Xf + (size_t)v * DD + 2 * lane);
        ax = s.x; ay = s.y;
      } else {
        const float2 s = unpk2(hu[(size_t)v * 64 + lane]);  // GIN self-term
        ax = s.x; ay = s.y;
        const int i0 = (v == 0) ? 0 : offE[v - 1];
        const int i1 = offE[v];
        int i = i0;
        for (; i + 4 <= i1; i += 4) {
          const int n0 = csr[i], n1 = csr[i + 1], n2 = csr[i + 2], n3 = csr[i + 3];
          const uint b0 = hu[(size_t)n0 * 64 + lane];
          const uint b1 = hu[(size_t)n1 * 64 + lane];
          const uint b2 = hu[(size_t)n2 * 64 + lane];
          const uint b3 = hu[(size_t)n3 * 64 + lane];
          const float2 f0 = unpk2(b0), f1 = unpk2(b1), f2 = unpk2(b2), f3 = unpk2(b3);
          ax += f0.x + f1.x + f2.x + f3.x;
          ay += f0.y + f1.y + f2.y + f3.y;
        }
        for (; i < i1; ++i) {
          const float2 f = unpk2(hu[(size_t)csr[i] * 64 + lane]);
          ax += f.x; ay += f.y;
        }
      }
    }
    uint hi2, lo2;
    split2(ax, ay, hi2, lo2);
    const int ch = lane >> 2;                       // col chunk (8 elems)
    const int uoff = (row * 16 + (ch ^ (row & 7))) * 4 + (lane & 3);
    ((uint*)AH)[uoff] = hi2;
    ((uint*)AL)[uoff] = lo2;
  }
  // no barrier: each wave reads only its own staged slice (lgkmcnt ordering)

  // ---- MFMA ----
  f32x4 acc[8];
#pragma unroll
  for (int nf = 0; nf < 8; ++nf) acc[nf] = (f32x4){0.f, 0.f, 0.f, 0.f};
  const int arow = w * 16 + (lane & 15);
  const int sw = arow & 7;
#pragma unroll
  for (int kk = 0; kk < 4; ++kk) {
    const int ch = kk * 4 + (lane >> 4);
    const int aidx = (arow * 16 + (ch ^ sw)) * 8;
    const short8v ah = *(const short8v*)&AH[aidx];
    const short8v al = *(const short8v*)&AL[aidx];
#pragma unroll
    for (int nf = 0; nf < 8; ++nf) {
      const ushort* bp = Wp + ((size_t)((kk * 8 + nf) * 2) * 64 + lane) * 8;
      const short8v bh = *(const short8v*)bp;
      const short8v bl = *(const short8v*)(bp + 64 * 8);
      acc[nf] = __builtin_amdgcn_mfma_f32_16x16x32_bf16(ah, bh, acc[nf], 0, 0, 0);
      acc[nf] = __builtin_amdgcn_mfma_f32_16x16x32_bf16(al, bh, acc[nf], 0, 0, 0);
      acc[nf] = __builtin_amdgcn_mfma_f32_16x16x32_bf16(ah, bl, acc[nf], 0, 0, 0);
    }
  }

  // ---- epilogue: bias + ReLU [+ LN], store bf16 ----
  const int colb = lane & 15;
  float bias8[8], g8[8], q8[8];
#pragma unroll
  for (int nf = 0; nf < 8; ++nf) {
    bias8[nf] = bias[nf * 16 + colb];
    if (MODE == 1) { g8[nf] = lng[nf * 16 + colb]; q8[nf] = lnb[nf * 16 + colb]; }
  }
#pragma unroll
  for (int r = 0; r < 4; ++r) {
    const int grow = r0 + w * 16 + (lane >> 4) * 4 + r;
    float z[8];
    float s = 0.f, s2 = 0.f;
#pragma unroll
    for (int nf = 0; nf < 8; ++nf) {
      z[nf] = fmaxf(acc[nf][r] + bias8[nf], 0.f);
      s += z[nf];
      s2 += z[nf] * z[nf];
    }
    if (MODE == 1) {
#pragma unroll
      for (int o = 1; o < 16; o <<= 1) { s += __shfl_xor(s, o); s2 += __shfl_xor(s2, o); }
      const float mu = s * (1.f / DD);
      const float inv = rsqrtf(s2 * (1.f / DD) - mu * mu + LN_EPS);
#pragma unroll
      for (int nf = 0; nf < 8; ++nf) z[nf] = (z[nf] - mu) * inv * g8[nf] + q8[nf];
    }
    if (grow < NN) {
      ushort* yp = Hout + (size_t)grow * DD + colb;
#pragma unroll
      for (int nf = 0; nf < 8; ++nf) {
        __hip_bfloat16 b = __float2bfloat16(z[nf]);
        yp[nf * 16] = *(ushort*)&b;
      }
    }
  }
}

// ============ pool (bf16 h, batch_ids sorted) ============
__global__ __launch_bounds__(128)
void pool_kernel(const ushort* __restrict__ h, const int* __restrict__ batch,
                 float* __restrict__ sums, float* __restrict__ counts) {
  const int c = threadIdx.x;
  const int base = blockIdx.x * 64;
  const int end = (base + 64 < NN) ? base + 64 : NN;
  int cur = batch[base];
  float acc = 0.f, cnt = 0.f;
  for (int r = base; r < end; ++r) {
    const int g = batch[r];
    if (g != cur) {
      __hip_atomic_fetch_add(&sums[cur * DD + c], acc, __ATOMIC_RELAXED, __HIP_MEMORY_SCOPE_AGENT);
      if (c == 0)
        __hip_atomic_fetch_add(&counts[cur], cnt, __ATOMIC_RELAXED, __HIP_MEMORY_SCOPE_AGENT);
      acc = 0.f; cnt = 0.f; cur = g;
    }
    acc += __uint_as_float(((uint)h[(size_t)r * DD + c]) << 16);
    cnt += 1.f;
  }
  __hip_atomic_fetch_add(&sums[cur * DD + c], acc, __ATOMIC_RELAXED, __HIP_MEMORY_SCOPE_AGENT);
  if (c == 0)
    __hip_atomic_fetch_add(&counts[cur], cnt, __ATOMIC_RELAXED, __HIP_MEMORY_SCOPE_AGENT);
}

__global__ __launch_bounds__(256)
void finalize_kernel(const float* __restrict__ sums, const float* __restrict__ counts,
                     float* __restrict__ out) {
  const int i = blockIdx.x * 256 + threadIdx.x;
  if (i >= NG * DD) return;
  out[i] = sums[i] / fmaxf(counts[i >> 7], 1.f);
}

extern "C" void kernel_launch(void* const* d_in, const int* in_sizes, int n_in,
                              void* d_out, int out_size, void* d_ws, size_t ws_size,
                              hipStream_t stream) {
  const float* x     = (const float*)d_in[0];
  const int*   ei    = (const int*)d_in[1];
  const int*   batch = (const int*)d_in[2];
  const float* projW = (const float*)d_in[3];
  const float* projb = (const float*)d_in[4];
  const float* mlpW  = (const float*)d_in[5];
  const float* mlpb  = (const float*)d_in[6];
  const float* lng   = (const float*)d_in[7];
  const float* lnb   = (const float*)d_in[8];
  float* out = (float*)d_out;

  char* ws = (char*)d_ws;
  ushort* hA    = (ushort*)(ws + 0);           // 25,600,000 B
  ushort* hB    = (ushort*)(ws + 25600000);    // 25,600,000 B
  int*   csr    = (int*)   (ws + 51200000);    //  2,400,000 B
  int*   deg    = (int*)   (ws + 53600000);    //    400,000 B
  int*   off    = (int*)   (ws + 54000000);    //    400,000 B
  int*   btot   = (int*)   (ws + 54400000);    //        512 B
  ushort* Wp    = (ushort*)(ws + 54400512);    //    262,144 B
  float* sums   = (float*) (ws + 54662656);    //     32,768 B
  float* counts = (float*) (ws + 54695424);    //        256 B

  const int* src = ei;
  const int* dst = ei + NE;

  // ---- CSR build ----
  hipMemsetAsync(deg, 0, NN * sizeof(int), stream);
  count_kernel<<<(NE + 255) / 256, 256, 0, stream>>>(dst, deg);
  scan_a<<<(NN + 1023) / 1024, 256, 0, stream>>>(deg, off, btot);
  scan_b<<<1, 128, 0, stream>>>(btot, (NN + 1023) / 1024);
  scan_c<<<(NN + 255) / 256, 256, 0, stream>>>(off, btot);
  fill_kernel<<<(NE + 255) / 256, 256, 0, stream>>>(src, dst, off, csr);

  // ---- weight prep ----
  wprep_kernel<<<32, 256, 0, stream>>>(projW, mlpW, Wp);

  const int gemm_blocks = (NN + 63) / 64;   // 1563

  // h = relu(x @ projW + projb) -> bf16
  gemm_node<0><<<gemm_blocks, 256, 0, stream>>>(
      x, nullptr, nullptr, nullptr, Wp, projb, nullptr, nullptr, hA);

  // 3 fused GIN layers, ping-pong hA/hB
  ushort* hin = hA;
  ushort* hout = hB;
  for (int l = 0; l < NL; ++l) {
    gemm_node<1><<<gemm_blocks, 256, 0, stream>>>(
        nullptr, hin, csr, off, Wp + (size_t)(1 + l) * 32768,
        mlpb + (size_t)l * DD, lng + (size_t)l * DD, lnb + (size_t)l * DD, hout);
    ushort* tmp = hin; hin = hout; hout = tmp;
  }

  hipMemsetAsync(sums, 0, (size_t)(NG * DD + NG) * sizeof(float), stream);
  pool_kernel<<<(NN + 63) / 64, 128, 0, stream>>>(hin, batch, sums, counts);
  finalize_kernel<<<(NG * DD + 255) / 256, 256, 0, stream>>>(sums, counts, out);
}